// Round 8
// baseline (315.791 us; speedup 1.0000x reference)
//
#include <hip/hip_runtime.h>
#include <hip/hip_cooperative_groups.h>
#include <stdint.h>

namespace cg = cooperative_groups;

static constexpr uint32_t SEQN = 4194304u;
static constexpr uint32_t BINS = 65536u;
static constexpr uint32_t QWORDS = BINS / 4u;       // u8x4-packed words
static constexpr uint32_t NBLK = 512u;              // 2 per CU (64 KiB LDS each)
static constexpr uint32_t NTHR = 1024u;
static constexpr uint32_t ROWS_PER_BLK = SEQN / NBLK;  // 8192

// ================= fused cooperative kernel =================
__global__ __launch_bounds__(NTHR, 8) void k_fused(const float4* __restrict__ in4,
                                                   float4* __restrict__ out4,
                                                   uint32_t* __restrict__ partial,
                                                   uint32_t* __restrict__ hist,
                                                   uint32_t* __restrict__ offs,
                                                   uint32_t* __restrict__ blkTot) {
  __shared__ __align__(16) uint32_t h[QWORDS];  // 64 KiB, re-used each phase
  __shared__ uint32_t wt[4];
  __shared__ uint32_t c_base;
  cg::grid_group grid = cg::this_grid();
  uint32_t tid = threadIdx.x, blk = blockIdx.x;

  // ---------- Phase A: LDS histogram + dump ----------
  {
    uint4* hv = (uint4*)h;
    for (uint32_t i = tid; i < QWORDS / 4u; i += NTHR) hv[i] = make_uint4(0u, 0u, 0u, 0u);
    __syncthreads();
    uint32_t q = tid & 3u;
    uint32_t shift = 12u - (q << 2);
    bool leader = (q == 0u);
    const float4* base = in4 + (size_t)blk * (ROWS_PER_BLK * 4u);
#pragma unroll 8
    for (uint32_t t = 0; t < (ROWS_PER_BLK * 4u) / NTHR; ++t) {  // 32 iters
      float4 v = base[(size_t)t * NTHR + tid];                   // 16 B/lane contiguous
      float nf = ((v.x * 2.0f + v.y) * 2.0f + v.z) * 2.0f + v.w;
      uint32_t part = ((uint32_t)nf) << shift;
      part += __shfl_xor(part, 1, 64);
      part += __shfl_xor(part, 2, 64);
      if (leader) atomicAdd(&h[part >> 2], 1u << ((part & 3u) << 3));
    }
    __syncthreads();
    uint4* dst = (uint4*)(partial + (size_t)blk * QWORDS);
    for (uint32_t i = tid; i < QWORDS / 4u; i += NTHR) dst[i] = hv[i];
  }
  grid.sync();

  // ---------- Phase B: reduce 512 partials -> hist + blkTot (blocks 0..63) ----------
  if (blk < 64u) {
    uint2* acc2 = (uint2*)h;  // [4][256]
    uint32_t wl = tid & 255u, g = tid >> 8;
    uint32_t w = blk * 256u + wl;
    uint32_t e = 0u, o = 0u;
    uint32_t p0 = g * (NBLK / 4u);
#pragma unroll 8
    for (uint32_t p = p0; p < p0 + NBLK / 4u; ++p) {
      uint32_t v = partial[(size_t)p * QWORDS + w];
      e += v & 0x00FF00FFu;
      o += (v >> 8) & 0x00FF00FFu;
    }
    acc2[g * 256u + wl] = make_uint2(e, o);
    __syncthreads();
    if (g == 0u) {
      uint2 a1 = acc2[256u + wl], a2 = acc2[512u + wl], a3 = acc2[768u + wl];
      e += a1.x + a2.x + a3.x;
      o += a1.y + a2.y + a3.y;
      uint32_t c0 = e & 0xFFFFu, c2 = e >> 16, c1 = o & 0xFFFFu, c3 = o >> 16;
      ((uint4*)hist)[w] = make_uint4(c0, c1, c2, c3);
      uint32_t ssum = c0 + c1 + c2 + c3;
      for (int d = 1; d < 64; d <<= 1) ssum += __shfl_xor(ssum, d, 64);
      if ((tid & 63u) == 0u) wt[tid >> 6] = ssum;
    }
    __syncthreads();
    if (tid == 0u) blkTot[blk] = wt[0] + wt[1] + wt[2] + wt[3];
  }
  grid.sync();

  // ---------- Phase C: offsets (blocks 0..63, first 256 threads) ----------
  if (blk < 64u && tid < 64u) {  // exclusive prefix over 64 block totals
    uint32_t v = blkTot[tid];
    uint32_t incl = v;
    for (int d = 1; d < 64; d <<= 1) {
      uint32_t n = __shfl_up(incl, d, 64);
      if (tid >= (uint32_t)d) incl += n;
    }
    if (tid == blk) c_base = incl - v;
  }
  __syncthreads();
  uint32_t c_s = 0u, c_incl = 0u;
  uint4 c_c = make_uint4(0u, 0u, 0u, 0u);
  if (blk < 64u && tid < 256u) {
    uint32_t lane = tid & 63u;
    uint32_t b0 = blk * 1024u + tid * 4u;
    c_c = ((const uint4*)hist)[b0 >> 2];
    c_s = c_c.x + c_c.y + c_c.z + c_c.w;
    c_incl = c_s;
    for (int d = 1; d < 64; d <<= 1) {
      uint32_t n = __shfl_up(c_incl, d, 64);
      if (lane >= (uint32_t)d) c_incl += n;
    }
    if (lane == 63u) wt[tid >> 6] = c_incl;
  }
  __syncthreads();
  if (blk < 64u && tid < 256u) {
    uint32_t wid = tid >> 6;
    uint32_t wbase = 0u;
    for (uint32_t w = 0; w < wid; ++w) wbase += wt[w];
    uint32_t base = c_base + wbase + (c_incl - c_s);
    uint32_t b0 = blk * 1024u + tid * 4u;
    ((uint4*)offs)[b0 >> 2] = make_uint4(base, base + c_c.x, base + c_c.x + c_c.y,
                                         base + c_c.x + c_c.y + c_c.z);
  }
  grid.sync();

  // ---------- Phase D: write (all 512 blocks, 128 keys each, plain stores) ----------
  {
    uint32_t* s_off = h;          // [128]
    uint32_t* s_cnt = h + 128u;   // [128]
    if (tid < 128u) {
      uint32_t k = blk * 128u + tid;
      s_off[tid] = offs[k];
      s_cnt[tid] = hist[k];
    }
    __syncthreads();
    uint32_t lane = tid & 63u, wid = tid >> 6;
    uint32_t q = lane & 3u;
    for (uint32_t kk = 0; kk < 8u; ++kk) {
      uint32_t ki = wid * 8u + kk;
      uint32_t k = blk * 128u + ki;
      uint32_t off = s_off[ki], cnt = s_cnt[ki];
      float4 pat;
      pat.x = (float)((k >> (15u - (q * 4u + 0u))) & 1u);
      pat.y = (float)((k >> (15u - (q * 4u + 1u))) & 1u);
      pat.z = (float)((k >> (15u - (q * 4u + 2u))) & 1u);
      pat.w = (float)((k >> (15u - (q * 4u + 3u))) & 1u);
      size_t base = (size_t)off * 4u;
      uint32_t tot = cnt * 4u;
      for (uint32_t j = lane; j < tot; j += 64u) out4[base + j] = pat;
    }
  }
}

// ================= fallback 4-kernel path (proven R5 pipeline) =================
__global__ __launch_bounds__(NTHR) void k_hist_lds(const float4* __restrict__ in4,
                                                   uint32_t* __restrict__ partial) {
  __shared__ __align__(16) uint32_t h[QWORDS];
  uint32_t tid = threadIdx.x, blk = blockIdx.x;
  uint4* hv = (uint4*)h;
  for (uint32_t i = tid; i < QWORDS / 4u; i += NTHR) hv[i] = make_uint4(0u, 0u, 0u, 0u);
  __syncthreads();
  uint32_t q = tid & 3u;
  uint32_t shift = 12u - (q << 2);
  bool leader = (q == 0u);
  const float4* base = in4 + (size_t)blk * (ROWS_PER_BLK * 4u);
#pragma unroll 8
  for (uint32_t t = 0; t < (ROWS_PER_BLK * 4u) / NTHR; ++t) {
    float4 v = base[(size_t)t * NTHR + tid];
    float nf = ((v.x * 2.0f + v.y) * 2.0f + v.z) * 2.0f + v.w;
    uint32_t part = ((uint32_t)nf) << shift;
    part += __shfl_xor(part, 1, 64);
    part += __shfl_xor(part, 2, 64);
    if (leader) atomicAdd(&h[part >> 2], 1u << ((part & 3u) << 3));
  }
  __syncthreads();
  uint4* dst = (uint4*)(partial + (size_t)blk * QWORDS);
  for (uint32_t i = tid; i < QWORDS / 4u; i += NTHR) dst[i] = hv[i];
}

__global__ __launch_bounds__(NTHR) void k_reduceB(const uint32_t* __restrict__ partial,
                                                  uint32_t* __restrict__ hist,
                                                  uint32_t* __restrict__ blkTot) {
  __shared__ uint2 acc[4][256];
  __shared__ uint32_t wt[4];
  uint32_t tid = threadIdx.x, blk = blockIdx.x;
  uint32_t wl = tid & 255u, g = tid >> 8;
  uint32_t w = blk * 256u + wl;
  uint32_t e = 0u, o = 0u;
  uint32_t p0 = g * (NBLK / 4u);
#pragma unroll 8
  for (uint32_t p = p0; p < p0 + NBLK / 4u; ++p) {
    uint32_t v = partial[(size_t)p * QWORDS + w];
    e += v & 0x00FF00FFu;
    o += (v >> 8) & 0x00FF00FFu;
  }
  acc[g][wl] = make_uint2(e, o);
  __syncthreads();
  if (g == 0u) {
    uint2 a1 = acc[1][wl], a2 = acc[2][wl], a3 = acc[3][wl];
    e += a1.x + a2.x + a3.x;
    o += a1.y + a2.y + a3.y;
    uint32_t c0 = e & 0xFFFFu, c2 = e >> 16, c1 = o & 0xFFFFu, c3 = o >> 16;
    ((uint4*)hist)[w] = make_uint4(c0, c1, c2, c3);
    uint32_t ssum = c0 + c1 + c2 + c3;
    for (int d = 1; d < 64; d <<= 1) ssum += __shfl_xor(ssum, d, 64);
    if ((tid & 63u) == 0u) wt[tid >> 6] = ssum;
  }
  __syncthreads();
  if (tid == 0u) blkTot[blk] = wt[0] + wt[1] + wt[2] + wt[3];
}

__global__ __launch_bounds__(256) void k_scanB(const uint32_t* __restrict__ hist,
                                               const uint32_t* __restrict__ blkTot,
                                               uint32_t* __restrict__ offs) {
  __shared__ uint32_t s_base;
  __shared__ uint32_t wt[4];
  uint32_t tid = threadIdx.x, blk = blockIdx.x;
  if (tid < 64u) {
    uint32_t v = blkTot[tid];
    uint32_t incl = v;
    for (int d = 1; d < 64; d <<= 1) {
      uint32_t n = __shfl_up(incl, d, 64);
      if (tid >= (uint32_t)d) incl += n;
    }
    if (tid == blk) s_base = incl - v;
  }
  __syncthreads();
  uint32_t lane = tid & 63u, wid = tid >> 6;
  uint32_t b0 = blk * 1024u + tid * 4u;
  uint4 c = ((const uint4*)hist)[b0 >> 2];
  uint32_t s = c.x + c.y + c.z + c.w;
  uint32_t incl = s;
  for (int d = 1; d < 64; d <<= 1) {
    uint32_t n = __shfl_up(incl, d, 64);
    if (lane >= (uint32_t)d) incl += n;
  }
  if (lane == 63u) wt[wid] = incl;
  __syncthreads();
  uint32_t wbase = 0u;
  for (uint32_t w = 0; w < wid; ++w) wbase += wt[w];
  uint32_t base = s_base + wbase + (incl - s);
  ((uint4*)offs)[b0 >> 2] = make_uint4(base, base + c.x, base + c.x + c.y,
                                       base + c.x + c.y + c.z);
}

__global__ __launch_bounds__(256) void k_write(const uint32_t* __restrict__ hist,
                                               const uint32_t* __restrict__ offs,
                                               float4* __restrict__ out4) {
  __shared__ uint32_t s_off[32], s_cnt[32];
  uint32_t tid = threadIdx.x, blk = blockIdx.x;
  if (tid < 32u) {
    uint32_t k = blk * 32u + tid;
    s_off[tid] = offs[k];
    s_cnt[tid] = hist[k];
  }
  __syncthreads();
  uint32_t lane = tid & 63u, wid = tid >> 6;
  uint32_t q = lane & 3u;
  for (uint32_t kk = 0; kk < 8u; ++kk) {
    uint32_t ki = wid * 8u + kk;
    uint32_t k = blk * 32u + ki;
    uint32_t off = s_off[ki], cnt = s_cnt[ki];
    float4 pat;
    pat.x = (float)((k >> (15u - (q * 4u + 0u))) & 1u);
    pat.y = (float)((k >> (15u - (q * 4u + 1u))) & 1u);
    pat.z = (float)((k >> (15u - (q * 4u + 2u))) & 1u);
    pat.w = (float)((k >> (15u - (q * 4u + 3u))) & 1u);
    size_t base = (size_t)off * 4u;
    uint32_t tot = cnt * 4u;
    for (uint32_t j = lane; j < tot; j += 64u) out4[base + j] = pat;
  }
}

extern "C" void kernel_launch(void* const* d_in, const int* in_sizes, int n_in,
                              void* d_out, int out_size, void* d_ws, size_t ws_size,
                              hipStream_t stream) {
  const float4* in4 = (const float4*)d_in[0];
  float4* out4 = (float4*)d_out;
  uint32_t* hist = (uint32_t*)d_ws;               // 65536 u32
  uint32_t* offs = hist + BINS;                   // 65536 u32
  uint32_t* blkTot = offs + BINS;                 // 64 u32 (pad to 1024)
  uint32_t* partial = blkTot + 1024u;             // NBLK * QWORDS u32 = 32 MiB

  size_t need = ((size_t)2 * BINS + 1024u + (size_t)NBLK * QWORDS) * 4u;
  bool coop_ok = false;
  if (ws_size >= need) {
    void* args[] = {(void*)&in4, (void*)&out4, (void*)&partial,
                    (void*)&hist, (void*)&offs, (void*)&blkTot};
    hipError_t err = hipLaunchCooperativeKernel((const void*)k_fused, dim3(NBLK),
                                                dim3(NTHR), args, 0, stream);
    coop_ok = (err == hipSuccess);
  }
  if (!coop_ok && ws_size >= need) {
    k_hist_lds<<<NBLK, NTHR, 0, stream>>>(in4, partial);
    k_reduceB<<<64, NTHR, 0, stream>>>(partial, hist, blkTot);
    k_scanB<<<64, 256, 0, stream>>>(hist, blkTot, offs);
    k_write<<<BINS / 32, 256, 0, stream>>>(hist, offs, out4);
  }
}

// Round 9
// 149.283 us; speedup vs baseline: 2.1154x; 2.1154x over previous
//
#include <hip/hip_runtime.h>
#include <stdint.h>

static constexpr uint32_t SEQN = 4194304u;
static constexpr uint32_t BINS = 65536u;
static constexpr uint32_t QWORDS = BINS / 4u;          // u8x4-packed words (16384)
static constexpr uint32_t NBLK = 256u;                 // 1 block/CU
static constexpr uint32_t NTHR = 1024u;                // 16 waves
static constexpr uint32_t ROWS_PER_BLK = SEQN / NBLK;  // 16384 (u8-safe: lambda=0.25)
static constexpr uint32_t ITERS = 32u;                 // per-wave chunks of 32 rows

__device__ __forceinline__ void gload16(const float4* g, uint32_t* lds) {
  __builtin_amdgcn_global_load_lds(
      (const __attribute__((address_space(1))) void*)g,
      (__attribute__((address_space(3))) void*)lds, 16, 0, 0);
}

// ---------- histogram: async global->LDS staging, per-wave pipeline ----------
__global__ __launch_bounds__(NTHR) void k_hist_lds(const float4* __restrict__ in4,
                                                   uint32_t* __restrict__ partial,
                                                   uint32_t* __restrict__ blkTot) {
  __shared__ __align__(16) uint32_t h[QWORDS];        // 64 KiB u8x4 counters
  __shared__ __align__(16) uint32_t stage[16384];     // 64 KiB: 16 waves x 2 bufs x 2 KiB
  uint32_t tid = threadIdx.x, blk = blockIdx.x;
  uint32_t lane = tid & 63u, wid = tid >> 6;
  if (blk == 0u && tid < 64u) blkTot[tid] = 0u;       // zero for reduce's atomics
  uint4* hv = (uint4*)h;
  for (uint32_t i = tid; i < QWORDS / 4u; i += NTHR) hv[i] = make_uint4(0u, 0u, 0u, 0u);
  __syncthreads();

  uint32_t q = lane & 3u;
  uint32_t shift = 12u - (q << 2);                    // quad q = bits [4q,4q+4) MSB-first
  bool leader = (q == 0u);
  // wave w owns rows [blk*16384 + w*1024, +1024): quads base:
  const float4* gbase = in4 + ((size_t)blk * 65536u + (size_t)wid * 4096u);
  uint32_t* sbase = stage + wid * 1024u;              // 2 bufs x 512 u32

  // prologue: issue chunk 0 into buf 0 (2 x 1KB per wave)
  gload16(gbase + lane, sbase);
  gload16(gbase + 64u + lane, sbase + 256u);

  for (uint32_t t = 0; t < ITERS; ++t) {
    if (t + 1u < ITERS) {  // issue chunk t+1 into the other buffer
      const float4* gp = gbase + (size_t)(t + 1u) * 128u;
      uint32_t* sp = sbase + ((t + 1u) & 1u) * 512u;
      gload16(gp + lane, sp);
      gload16(gp + 64u + lane, sp + 256u);
      asm volatile("s_waitcnt vmcnt(2)" ::: "memory");  // chunk t landed
    } else {
      asm volatile("s_waitcnt vmcnt(0)" ::: "memory");
    }
    uint32_t* cb = sbase + (t & 1u) * 512u;
#pragma unroll
    for (uint32_t r = 0; r < 2u; ++r) {
      float4 v = *(const float4*)(cb + r * 256u + lane * 4u);  // lane-linear: no conflicts
      float nf = ((v.x * 2.0f + v.y) * 2.0f + v.z) * 2.0f + v.w;
      uint32_t part = ((uint32_t)nf) << shift;
      part += __shfl_xor(part, 1, 64);
      part += __shfl_xor(part, 2, 64);  // all 4 lanes hold full 16-bit key
      if (leader) atomicAdd(&h[part >> 2], 1u << ((part & 3u) << 3));
    }
  }
  __syncthreads();
  uint4* dst = (uint4*)(partial + (size_t)blk * QWORDS);
  for (uint32_t i = tid; i < QWORDS / 4u; i += NTHR) dst[i] = hv[i];
}

// ---------- reduce: 256 blocks x 256 thr; block b sums words [b*64,b*64+64) ----------
__global__ __launch_bounds__(256) void k_reduceC(const uint32_t* __restrict__ partial,
                                                 uint32_t* __restrict__ hist,
                                                 uint32_t* __restrict__ blkTot) {
  __shared__ uint2 acc[4][64];
  uint32_t tid = threadIdx.x, b = blockIdx.x;
  uint32_t wl = tid & 63u, g = tid >> 6;
  uint32_t w = b * 64u + wl;
  uint32_t e = 0u, o = 0u;  // packed u16 pairs: (4w,4w+2)/(4w+1,4w+3); 256x255 < 65536
  uint32_t p0 = g * (NBLK / 4u);
#pragma unroll 8
  for (uint32_t p = p0; p < p0 + NBLK / 4u; ++p) {
    uint32_t v = partial[(size_t)p * QWORDS + w];
    e += v & 0x00FF00FFu;
    o += (v >> 8) & 0x00FF00FFu;
  }
  acc[g][wl] = make_uint2(e, o);
  __syncthreads();
  if (g == 0u) {
    uint2 a1 = acc[1][wl], a2 = acc[2][wl], a3 = acc[3][wl];
    e += a1.x + a2.x + a3.x;
    o += a1.y + a2.y + a3.y;
    uint32_t c0 = e & 0xFFFFu, c2 = e >> 16, c1 = o & 0xFFFFu, c3 = o >> 16;
    ((uint4*)hist)[w] = make_uint4(c0, c1, c2, c3);
    uint32_t ssum = c0 + c1 + c2 + c3;
    for (int d = 1; d < 64; d <<= 1) ssum += __shfl_xor(ssum, d, 64);
    if (wl == 0u) atomicAdd(&blkTot[b >> 2], ssum);  // 4 blocks per 1024-bin entry
  }
}

// ---------- fallback global-atomic histogram (small ws) ----------
__global__ __launch_bounds__(256) void k_zero(uint32_t* __restrict__ hist,
                                              uint32_t* __restrict__ blkTot) {
  uint32_t i = blockIdx.x * 256u + threadIdx.x;
  if (i < BINS) hist[i] = 0u;
  if (i < 64u) blkTot[i] = 0u;
}

__global__ __launch_bounds__(256) void k_hist(const float4* __restrict__ in4,
                                              uint32_t* __restrict__ hist) {
  uint32_t r = blockIdx.x * 256u + threadIdx.x;
  if (r >= SEQN) return;
  uint32_t key = 0u;
#pragma unroll
  for (uint32_t qq = 0; qq < 4u; ++qq) {
    float4 v = in4[(size_t)r * 4u + qq];
    uint32_t nib = ((uint32_t)v.x << 3) | ((uint32_t)v.y << 2) |
                   ((uint32_t)v.z << 1) | (uint32_t)v.w;
    key = (key << 4) | nib;
  }
  atomicAdd(&hist[key], 1u);
}

__global__ __launch_bounds__(256) void k_scan1(const uint32_t* __restrict__ hist,
                                               uint32_t* __restrict__ blkTot) {
  uint32_t tid = threadIdx.x, blk = blockIdx.x;
  uint32_t b0 = blk * 1024u + tid * 4u;
  uint32_t s = hist[b0] + hist[b0 + 1] + hist[b0 + 2] + hist[b0 + 3];
  for (int d = 1; d < 64; d <<= 1) s += __shfl_xor(s, d, 64);
  __shared__ uint32_t wt[4];
  if ((tid & 63u) == 0u) wt[tid >> 6] = s;
  __syncthreads();
  if (tid == 0u) blkTot[blk] = wt[0] + wt[1] + wt[2] + wt[3];
}

// ---------- fused scan: block base from blkTot, then per-bin offsets ----------
__global__ __launch_bounds__(256) void k_scanB(const uint32_t* __restrict__ hist,
                                               const uint32_t* __restrict__ blkTot,
                                               uint32_t* __restrict__ offs) {
  __shared__ uint32_t s_base;
  __shared__ uint32_t wt[4];
  uint32_t tid = threadIdx.x, blk = blockIdx.x;
  if (tid < 64u) {
    uint32_t v = blkTot[tid];
    uint32_t incl = v;
    for (int d = 1; d < 64; d <<= 1) {
      uint32_t n = __shfl_up(incl, d, 64);
      if (tid >= (uint32_t)d) incl += n;
    }
    if (tid == blk) s_base = incl - v;
  }
  __syncthreads();
  uint32_t lane = tid & 63u, wid = tid >> 6;
  uint32_t b0 = blk * 1024u + tid * 4u;
  uint4 c = ((const uint4*)hist)[b0 >> 2];
  uint32_t s = c.x + c.y + c.z + c.w;
  uint32_t incl = s;
  for (int d = 1; d < 64; d <<= 1) {
    uint32_t n = __shfl_up(incl, d, 64);
    if (lane >= (uint32_t)d) incl += n;
  }
  if (lane == 63u) wt[wid] = incl;
  __syncthreads();
  uint32_t wbase = 0u;
  for (uint32_t w = 0; w < wid; ++w) wbase += wt[w];
  uint32_t base = s_base + wbase + (incl - s);
  ((uint4*)offs)[b0 >> 2] = make_uint4(base, base + c.x, base + c.x + c.y,
                                       base + c.x + c.y + c.z);
}

// ---------- writer: wave-autonomous, 8 keys/wave, plain stores ----------
__global__ __launch_bounds__(256) void k_write(const uint32_t* __restrict__ hist,
                                               const uint32_t* __restrict__ offs,
                                               float4* __restrict__ out4) {
  __shared__ uint32_t s_off[32], s_cnt[32];
  uint32_t tid = threadIdx.x, blk = blockIdx.x;
  if (tid < 32u) {
    uint32_t k = blk * 32u + tid;
    s_off[tid] = offs[k];
    s_cnt[tid] = hist[k];
  }
  __syncthreads();
  uint32_t lane = tid & 63u, wid = tid >> 6;
  uint32_t q = lane & 3u;
  for (uint32_t kk = 0; kk < 8u; ++kk) {
    uint32_t ki = wid * 8u + kk;
    uint32_t k = blk * 32u + ki;
    uint32_t off = s_off[ki], cnt = s_cnt[ki];
    float4 pat;
    pat.x = (float)((k >> (15u - (q * 4u + 0u))) & 1u);
    pat.y = (float)((k >> (15u - (q * 4u + 1u))) & 1u);
    pat.z = (float)((k >> (15u - (q * 4u + 2u))) & 1u);
    pat.w = (float)((k >> (15u - (q * 4u + 3u))) & 1u);
    size_t base = (size_t)off * 4u;
    uint32_t tot = cnt * 4u;
    for (uint32_t j = lane; j < tot; j += 64u) out4[base + j] = pat;
  }
}

extern "C" void kernel_launch(void* const* d_in, const int* in_sizes, int n_in,
                              void* d_out, int out_size, void* d_ws, size_t ws_size,
                              hipStream_t stream) {
  const float4* in4 = (const float4*)d_in[0];
  float4* out4 = (float4*)d_out;
  uint32_t* hist = (uint32_t*)d_ws;               // 65536 u32
  uint32_t* offs = hist + BINS;                   // 65536 u32
  uint32_t* blkTot = offs + BINS;                 // 64 u32 (pad to 1024)
  uint32_t* partial = blkTot + 1024u;             // NBLK * QWORDS u32 = 16 MiB

  size_t need = ((size_t)2 * BINS + 1024u + (size_t)NBLK * QWORDS) * 4u;
  if (ws_size >= need) {
    k_hist_lds<<<NBLK, NTHR, 0, stream>>>(in4, partial, blkTot);
    k_reduceC<<<256, 256, 0, stream>>>(partial, hist, blkTot);
  } else {
    k_zero<<<BINS / 256, 256, 0, stream>>>(hist, blkTot);
    k_hist<<<SEQN / 256, 256, 0, stream>>>(in4, hist);
    k_scan1<<<64, 256, 0, stream>>>(hist, blkTot);
  }
  k_scanB<<<64, 256, 0, stream>>>(hist, blkTot, offs);
  k_write<<<BINS / 32, 256, 0, stream>>>(hist, offs, out4);
}

// Round 10
// 141.674 us; speedup vs baseline: 2.2290x; 1.0537x over previous
//
#include <hip/hip_runtime.h>
#include <stdint.h>

static constexpr uint32_t SEQN = 4194304u;
static constexpr uint32_t BINS = 65536u;
static constexpr uint32_t QWORDS = BINS / 4u;       // u8x4-packed words
static constexpr uint32_t NBLK = 512u;              // 2 per CU (64 KiB LDS each)
static constexpr uint32_t NTHR = 1024u;
static constexpr uint32_t ROWS_PER_BLK = SEQN / NBLK;  // 8192 (u8-safe)

// ---------- LDS-privatized histogram: batch-8 loads + DPP key assembly ----------
// No lgkmcnt-entangled ops in the loop: shfl_xor replaced by quad_perm DPP adds
// (VALU-only), so 8 global loads stay in flight per lane.
__global__ __launch_bounds__(NTHR) void k_hist_lds(const float4* __restrict__ in4,
                                                   uint32_t* __restrict__ partial) {
  __shared__ __align__(16) uint32_t h[QWORDS];  // 64 KiB u8x4 counters
  uint32_t tid = threadIdx.x, blk = blockIdx.x;
  uint4* hv = (uint4*)h;
  for (uint32_t i = tid; i < QWORDS / 4u; i += NTHR) hv[i] = make_uint4(0u, 0u, 0u, 0u);
  __syncthreads();
  uint32_t q = tid & 3u;
  uint32_t shift = 12u - (q << 2);        // quad q covers bits [4q,4q+4) MSB-first
  bool leader = (q == 0u);
  const float4* base = in4 + (size_t)blk * (ROWS_PER_BLK * 4u);
#pragma unroll
  for (uint32_t b = 0; b < 4u; ++b) {
    float4 v[8];
#pragma unroll
    for (uint32_t u = 0; u < 8u; ++u)       // 8 independent coalesced 16B loads
      v[u] = base[(size_t)(b * 8u + u) * NTHR + tid];
#pragma unroll
    for (uint32_t u = 0; u < 8u; ++u) {
      float nf = ((v[u].x * 2.0f + v[u].y) * 2.0f + v[u].z) * 2.0f + v[u].w;
      uint32_t part = ((uint32_t)nf) << shift;
      // quad_perm [1,0,3,2] then [2,3,0,1]: all 4 lanes assemble the full key, VALU-only
      uint32_t s1 = part + (uint32_t)__builtin_amdgcn_mov_dpp((int)part, 0xB1, 0xF, 0xF, true);
      uint32_t key = s1 + (uint32_t)__builtin_amdgcn_mov_dpp((int)s1, 0x4E, 0xF, 0xF, true);
      if (leader) atomicAdd(&h[key >> 2], 1u << ((key & 3u) << 3));
    }
  }
  __syncthreads();
  uint4* dst = (uint4*)(partial + (size_t)blk * QWORDS);
  for (uint32_t i = tid; i < QWORDS / 4u; i += NTHR) dst[i] = hv[i];
}

// ---------- fused reduce (512-fan-in) + hist + per-1024-bin totals ----------
__global__ __launch_bounds__(NTHR) void k_reduceB(const uint32_t* __restrict__ partial,
                                                  uint32_t* __restrict__ hist,
                                                  uint32_t* __restrict__ blkTot) {
  __shared__ uint2 acc[4][256];
  __shared__ uint32_t wt[4];
  uint32_t tid = threadIdx.x, blk = blockIdx.x;
  uint32_t wl = tid & 255u, g = tid >> 8;
  uint32_t w = blk * 256u + wl;
  uint32_t e = 0u, o = 0u;
  uint32_t p0 = g * (NBLK / 4u);
#pragma unroll 8
  for (uint32_t p = p0; p < p0 + NBLK / 4u; ++p) {
    uint32_t v = partial[(size_t)p * QWORDS + w];
    e += v & 0x00FF00FFu;
    o += (v >> 8) & 0x00FF00FFu;
  }
  acc[g][wl] = make_uint2(e, o);
  __syncthreads();
  if (g == 0u) {
    uint2 a1 = acc[1][wl], a2 = acc[2][wl], a3 = acc[3][wl];
    e += a1.x + a2.x + a3.x;
    o += a1.y + a2.y + a3.y;
    uint32_t c0 = e & 0xFFFFu, c2 = e >> 16, c1 = o & 0xFFFFu, c3 = o >> 16;
    ((uint4*)hist)[w] = make_uint4(c0, c1, c2, c3);
    uint32_t ssum = c0 + c1 + c2 + c3;
    for (int d = 1; d < 64; d <<= 1) ssum += __shfl_xor(ssum, d, 64);
    if ((tid & 63u) == 0u) wt[tid >> 6] = ssum;
  }
  __syncthreads();
  if (tid == 0u) blkTot[blk] = wt[0] + wt[1] + wt[2] + wt[3];
}

// ---------- fallback global-atomic histogram (small ws) ----------
__global__ __launch_bounds__(256) void k_zero(uint32_t* __restrict__ hist) {
  uint32_t i = blockIdx.x * 256u + threadIdx.x;
  if (i < BINS) hist[i] = 0u;
}

__global__ __launch_bounds__(256) void k_hist(const float4* __restrict__ in4,
                                              uint32_t* __restrict__ hist) {
  uint32_t r = blockIdx.x * 256u + threadIdx.x;
  if (r >= SEQN) return;
  uint32_t key = 0u;
#pragma unroll
  for (uint32_t qq = 0; qq < 4u; ++qq) {
    float4 v = in4[(size_t)r * 4u + qq];
    uint32_t nib = ((uint32_t)v.x << 3) | ((uint32_t)v.y << 2) |
                   ((uint32_t)v.z << 1) | (uint32_t)v.w;
    key = (key << 4) | nib;
  }
  atomicAdd(&hist[key], 1u);
}

__global__ __launch_bounds__(256) void k_scan1(const uint32_t* __restrict__ hist,
                                               uint32_t* __restrict__ blkTot) {
  uint32_t tid = threadIdx.x, blk = blockIdx.x;
  uint32_t b0 = blk * 1024u + tid * 4u;
  uint32_t s = hist[b0] + hist[b0 + 1] + hist[b0 + 2] + hist[b0 + 3];
  for (int d = 1; d < 64; d <<= 1) s += __shfl_xor(s, d, 64);
  __shared__ uint32_t wt[4];
  if ((tid & 63u) == 0u) wt[tid >> 6] = s;
  __syncthreads();
  if (tid == 0u) blkTot[blk] = wt[0] + wt[1] + wt[2] + wt[3];
}

// ---------- fused scan: block base from blkTot, then per-bin offsets ----------
__global__ __launch_bounds__(256) void k_scanB(const uint32_t* __restrict__ hist,
                                               const uint32_t* __restrict__ blkTot,
                                               uint32_t* __restrict__ offs) {
  __shared__ uint32_t s_base;
  __shared__ uint32_t wt[4];
  uint32_t tid = threadIdx.x, blk = blockIdx.x;
  if (tid < 64u) {
    uint32_t v = blkTot[tid];
    uint32_t incl = v;
    for (int d = 1; d < 64; d <<= 1) {
      uint32_t n = __shfl_up(incl, d, 64);
      if (tid >= (uint32_t)d) incl += n;
    }
    if (tid == blk) s_base = incl - v;
  }
  __syncthreads();
  uint32_t lane = tid & 63u, wid = tid >> 6;
  uint32_t b0 = blk * 1024u + tid * 4u;
  uint4 c = ((const uint4*)hist)[b0 >> 2];
  uint32_t s = c.x + c.y + c.z + c.w;
  uint32_t incl = s;
  for (int d = 1; d < 64; d <<= 1) {
    uint32_t n = __shfl_up(incl, d, 64);
    if (lane >= (uint32_t)d) incl += n;
  }
  if (lane == 63u) wt[wid] = incl;
  __syncthreads();
  uint32_t wbase = 0u;
  for (uint32_t w = 0; w < wid; ++w) wbase += wt[w];
  uint32_t base = s_base + wbase + (incl - s);
  ((uint4*)offs)[b0 >> 2] = make_uint4(base, base + c.x, base + c.x + c.y,
                                       base + c.x + c.y + c.z);
}

// ---------- writer: wave-autonomous, 8 keys/wave ----------
__global__ __launch_bounds__(256) void k_write(const uint32_t* __restrict__ hist,
                                               const uint32_t* __restrict__ offs,
                                               float4* __restrict__ out4) {
  __shared__ uint32_t s_off[32], s_cnt[32];
  uint32_t tid = threadIdx.x, blk = blockIdx.x;
  if (tid < 32u) {
    uint32_t k = blk * 32u + tid;
    s_off[tid] = offs[k];
    s_cnt[tid] = hist[k];
  }
  __syncthreads();
  uint32_t lane = tid & 63u, wid = tid >> 6;
  uint32_t q = lane & 3u;
  for (uint32_t kk = 0; kk < 8u; ++kk) {
    uint32_t ki = wid * 8u + kk;
    uint32_t k = blk * 32u + ki;
    uint32_t off = s_off[ki], cnt = s_cnt[ki];
    float4 pat;
    pat.x = (float)((k >> (15u - (q * 4u + 0u))) & 1u);
    pat.y = (float)((k >> (15u - (q * 4u + 1u))) & 1u);
    pat.z = (float)((k >> (15u - (q * 4u + 2u))) & 1u);
    pat.w = (float)((k >> (15u - (q * 4u + 3u))) & 1u);
    size_t base = (size_t)off * 4u;
    uint32_t tot = cnt * 4u;
    for (uint32_t j = lane; j < tot; j += 64u) out4[base + j] = pat;
  }
}

extern "C" void kernel_launch(void* const* d_in, const int* in_sizes, int n_in,
                              void* d_out, int out_size, void* d_ws, size_t ws_size,
                              hipStream_t stream) {
  const float4* in4 = (const float4*)d_in[0];
  float4* out4 = (float4*)d_out;
  uint32_t* hist = (uint32_t*)d_ws;               // 65536 u32
  uint32_t* offs = hist + BINS;                   // 65536 u32
  uint32_t* blkTot = offs + BINS;                 // 64 u32 (pad to 1024)
  uint32_t* partial = blkTot + 1024u;             // NBLK * QWORDS u32 = 32 MiB

  size_t need = ((size_t)2 * BINS + 1024u + (size_t)NBLK * QWORDS) * 4u;
  if (ws_size >= need) {
    k_hist_lds<<<NBLK, NTHR, 0, stream>>>(in4, partial);
    k_reduceB<<<64, NTHR, 0, stream>>>(partial, hist, blkTot);
  } else {
    k_zero<<<BINS / 256, 256, 0, stream>>>(hist);
    k_hist<<<SEQN / 256, 256, 0, stream>>>(in4, hist);
    k_scan1<<<64, 256, 0, stream>>>(hist, blkTot);
  }
  k_scanB<<<64, 256, 0, stream>>>(hist, blkTot, offs);
  k_write<<<BINS / 32, 256, 0, stream>>>(hist, offs, out4);
}